// Round 1
// baseline (3104.601 us; speedup 1.0000x reference)
//
#include <hip/hip_runtime.h>
#include <math.h>

// VariableSelectionNetwork — round 0: correct fp32 baseline.
// B=256, T=128, F=4, H=512. Heavy part: 2 chained GEMMs (M=32768,K=N=512) x F=4
// = 137.4 GFLOP fp32 -> ideal 875us at 157TF vector; predict ~1.1-1.3ms.
// Round 1 plan: bf16 MFMA conversion of kernel B.

#define H 512
#define NF 4
#define NT 128
#define NB 256
#define MTOT (NB * NT)   // 32768 rows (b,t)
#define TM 16            // rows per block tile
#define BK 8             // K chunk staged in LDS
#define NTHR 256

__device__ __forceinline__ float elu_f(float x) { return x > 0.0f ? x : expm1f(x); }
__device__ __forceinline__ float sigmoid_f(float x) { return 1.0f / (1.0f + expf(-x)); }

// ---------------- Kernel A: context GRN + softmax selection ----------------
// one block per batch b, 512 threads (thread = h index)
__global__ __launch_bounds__(512)
void ctx_grn_kernel(const float* __restrict__ in,
                    const float* __restrict__ W1c, const float* __restrict__ b1c,
                    const float* __restrict__ W2c, const float* __restrict__ b2c,
                    const float* __restrict__ Wgc, const float* __restrict__ bgc,
                    const float* __restrict__ gamma_c, const float* __restrict__ beta_c,
                    const float* __restrict__ Wsel, const float* __restrict__ bsel,
                    float* __restrict__ sel_ws,      // [B, F]
                    float* __restrict__ selw_out)    // [B, T, 1, F] flat
{
  __shared__ float sFlat[H];
  __shared__ float sX[H];
  __shared__ float sX2[H];
  __shared__ float sPartS[8], sPartQ[8];
  __shared__ float sLog[8][NF];
  __shared__ float sSel[NF];

  const int b = blockIdx.x;
  const int tid = threadIdx.x;

  sFlat[tid] = in[b * H + tid];   // flat[d] with d = t*F+f, contiguous
  __syncthreads();

  // dense1 + elu
  float acc = b1c[tid];
  #pragma unroll 8
  for (int d = 0; d < H; ++d) acc = fmaf(sFlat[d], W1c[d * H + tid], acc);
  sX[tid] = elu_f(acc);
  __syncthreads();

  // dense2
  acc = b2c[tid];
  #pragma unroll 8
  for (int d = 0; d < H; ++d) acc = fmaf(sX[d], W2c[d * H + tid], acc);
  sX2[tid] = acc;
  __syncthreads();

  // gate
  acc = bgc[tid];
  #pragma unroll 8
  for (int d = 0; d < H; ++d) acc = fmaf(sX2[d], Wgc[d * H + tid], acc);
  const float g = sigmoid_f(acc);
  const float y = g * sX2[tid] + (1.0f - g) * sFlat[tid];

  // LayerNorm over 512 (block reduce: wave shuffle + 8 wave partials)
  float s = y, q = y * y;
  #pragma unroll
  for (int m = 32; m >= 1; m >>= 1) { s += __shfl_xor(s, m, 64); q += __shfl_xor(q, m, 64); }
  const int wid = tid >> 6;
  if ((tid & 63) == 0) { sPartS[wid] = s; sPartQ[wid] = q; }
  __syncthreads();
  s = 0.0f; q = 0.0f;
  #pragma unroll
  for (int w = 0; w < 8; ++w) { s += sPartS[w]; q += sPartQ[w]; }
  const float mean = s * (1.0f / H);
  const float var  = q * (1.0f / H) - mean * mean;
  const float rstd = rsqrtf(var + 1e-3f);
  const float ctx  = gamma_c[tid] * ((y - mean) * rstd) + beta_c[tid];

  // selection logits: z[f] = sum_h ctx[h]*Wsel[h,f] + bsel[f]
  float p0 = ctx * Wsel[tid * NF + 0];
  float p1 = ctx * Wsel[tid * NF + 1];
  float p2 = ctx * Wsel[tid * NF + 2];
  float p3 = ctx * Wsel[tid * NF + 3];
  #pragma unroll
  for (int m = 32; m >= 1; m >>= 1) {
    p0 += __shfl_xor(p0, m, 64); p1 += __shfl_xor(p1, m, 64);
    p2 += __shfl_xor(p2, m, 64); p3 += __shfl_xor(p3, m, 64);
  }
  if ((tid & 63) == 0) { sLog[wid][0] = p0; sLog[wid][1] = p1; sLog[wid][2] = p2; sLog[wid][3] = p3; }
  __syncthreads();
  if (tid == 0) {
    float z[NF];
    for (int f = 0; f < NF; ++f) {
      float t = bsel[f];
      for (int w = 0; w < 8; ++w) t += sLog[w][f];
      z[f] = t;
    }
    float mx = fmaxf(fmaxf(z[0], z[1]), fmaxf(z[2], z[3]));
    float e[NF]; float se = 0.0f;
    for (int f = 0; f < NF; ++f) { e[f] = expf(z[f] - mx); se += e[f]; }
    float inv = 1.0f / se;
    for (int f = 0; f < NF; ++f) sSel[f] = e[f] * inv;
  }
  __syncthreads();
  if (tid < NF) sel_ws[b * NF + tid] = sSel[tid];
  // sel_weights output: [B,T,1,F], index b*512 + t*4 + f == b*512 + tid
  selw_out[b * H + tid] = sSel[tid & 3];
}

// ------------- Kernel B: per-variable GRNs + weighted selection -------------
// block = 256 threads, handles TM=16 rows for ALL 4 variables (fused GEMM1 ->
// LDS X2 tile -> GEMM2 -> gate/LN/weighted-sum epilogue). LDS ~49.4KB -> 3 blk/CU.
__global__ __launch_bounds__(NTHR)
void var_grn_kernel(const float* __restrict__ in,     // [MTOT, F]
                    const float* __restrict__ w1, const float* __restrict__ b1,
                    const float* __restrict__ W2, const float* __restrict__ b2,
                    const float* __restrict__ Wg, const float* __restrict__ bg,
                    const float* __restrict__ gamma, const float* __restrict__ beta,
                    const float* __restrict__ sel_ws, // [B, F]
                    float* __restrict__ out)          // [MTOT, H]
{
  __shared__ __align__(16) float sA[BK][TM];
  __shared__ __align__(16) float sB[BK][H];
  __shared__ __align__(16) float sX2[TM][H + 1];  // +1 pad: conflict-free column reads
  __shared__ float sV[TM];

  const int tid  = threadIdx.x;
  const int tidn = tid & 31;        // 32 threads across N
  const int tidm = tid >> 5;        // 8 thread-rows
  const int m0   = tidm * 2;        // 2 rows per thread
  const int row0 = blockIdx.x * TM;
  const int bidx = row0 >> 7;       // batch index (TM divides T -> constant per block)

  float outacc[2][16];
  #pragma unroll
  for (int r = 0; r < 2; ++r)
    #pragma unroll
    for (int c = 0; c < 16; ++c) outacc[r][c] = 0.0f;

  for (int f = 0; f < NF; ++f) {
    const float* __restrict__ W2f = W2 + f * H * H;
    const float* __restrict__ Wgf = Wg + f * H * H;
    const float* __restrict__ w1f = w1 + f * H;
    const float* __restrict__ b1f = b1 + f * H;
    const float* __restrict__ b2f = b2 + f * H;
    const float* __restrict__ bgf = bg + f * H;
    const float* __restrict__ gmf = gamma + f * H;
    const float* __restrict__ btf = beta + f * H;

    if (tid < TM) sV[tid] = in[(row0 + tid) * NF + f];

    float acc[2][16];
    #pragma unroll
    for (int r = 0; r < 2; ++r)
      #pragma unroll
      for (int c = 0; c < 16; ++c) acc[r][c] = 0.0f;

    __syncthreads();  // sV visible (also separates from prev f's epilogue reads)

    // ---- GEMM1: X2 = elu(v*w1+b1) @ W2f  (+b2 in epilogue) ----
    for (int kk = 0; kk < H; kk += BK) {
      if (tid < BK * TM) {                       // 128 threads build A chunk
        int k = tid >> 4, m = tid & 15;
        sA[k][m] = elu_f(fmaf(sV[m], w1f[kk + k], b1f[kk + k]));
      }
      #pragma unroll
      for (int j = 0; j < 4; ++j) {              // stage B chunk: 8x512 floats
        int i = tid + j * NTHR;                  // 0..1023 float4s
        int k = i >> 7, n4 = i & 127;
        *(float4*)&sB[k][n4 * 4] = *(const float4*)&W2f[(kk + k) * H + n4 * 4];
      }
      __syncthreads();
      #pragma unroll
      for (int k = 0; k < BK; ++k) {
        float2 a = *(const float2*)&sA[k][m0];
        const float* bp = &sB[k][tidn * 4];
        float4 b0 = *(const float4*)(bp);
        float4 b1v = *(const float4*)(bp + 128);
        float4 b2v = *(const float4*)(bp + 256);
        float4 b3v = *(const float4*)(bp + 384);
        float bv[16] = { b0.x,b0.y,b0.z,b0.w, b1v.x,b1v.y,b1v.z,b1v.w,
                         b2v.x,b2v.y,b2v.z,b2v.w, b3v.x,b3v.y,b3v.z,b3v.w };
        #pragma unroll
        for (int c = 0; c < 16; ++c) {
          acc[0][c] = fmaf(a.x, bv[c], acc[0][c]);
          acc[1][c] = fmaf(a.y, bv[c], acc[1][c]);
        }
      }
      __syncthreads();
    }

    // epilogue1: +b2, park X2 tile in LDS
    #pragma unroll
    for (int c = 0; c < 16; ++c) {
      int n = tidn * 4 + (c >> 2) * 128 + (c & 3);
      float bb = b2f[n];
      sX2[m0 + 0][n] = acc[0][c] + bb;
      sX2[m0 + 1][n] = acc[1][c] + bb;
    }
    __syncthreads();

    // ---- GEMM2: Gpre = X2 @ Wgf  (+bg in epilogue) ----
    #pragma unroll
    for (int r = 0; r < 2; ++r)
      #pragma unroll
      for (int c = 0; c < 16; ++c) acc[r][c] = 0.0f;

    for (int kk = 0; kk < H; kk += BK) {
      #pragma unroll
      for (int j = 0; j < 4; ++j) {
        int i = tid + j * NTHR;
        int k = i >> 7, n4 = i & 127;
        *(float4*)&sB[k][n4 * 4] = *(const float4*)&Wgf[(kk + k) * H + n4 * 4];
      }
      __syncthreads();
      #pragma unroll
      for (int k = 0; k < BK; ++k) {
        float a0 = sX2[m0 + 0][kk + k];
        float a1 = sX2[m0 + 1][kk + k];
        const float* bp = &sB[k][tidn * 4];
        float4 b0 = *(const float4*)(bp);
        float4 b1v = *(const float4*)(bp + 128);
        float4 b2v = *(const float4*)(bp + 256);
        float4 b3v = *(const float4*)(bp + 384);
        float bv[16] = { b0.x,b0.y,b0.z,b0.w, b1v.x,b1v.y,b1v.z,b1v.w,
                         b2v.x,b2v.y,b2v.z,b2v.w, b3v.x,b3v.y,b3v.z,b3v.w };
        #pragma unroll
        for (int c = 0; c < 16; ++c) {
          acc[0][c] = fmaf(a0, bv[c], acc[0][c]);
          acc[1][c] = fmaf(a1, bv[c], acc[1][c]);
        }
      }
      __syncthreads();
    }

    // epilogue2: gate -> gated (in-place in acc) -> LayerNorm -> weighted sum
    const float selw = sel_ws[bidx * NF + f];
    float rs[2] = {0.0f, 0.0f}, rq[2] = {0.0f, 0.0f};
    #pragma unroll
    for (int c = 0; c < 16; ++c) {
      int n = tidn * 4 + (c >> 2) * 128 + (c & 3);
      float bb = bgf[n];
      #pragma unroll
      for (int r = 0; r < 2; ++r) {
        float x2v = sX2[m0 + r][n];
        float gv  = sigmoid_f(acc[r][c] + bb);
        float gt  = gv * x2v + (1.0f - gv) * sV[m0 + r];
        acc[r][c] = gt;
        rs[r] += gt; rq[r] += gt * gt;
      }
    }
    // row reduce across the 32 tidn lanes (xor masks stay within 32-lane halves)
    #pragma unroll
    for (int msk = 16; msk >= 1; msk >>= 1) {
      #pragma unroll
      for (int r = 0; r < 2; ++r) {
        rs[r] += __shfl_xor(rs[r], msk, 64);
        rq[r] += __shfl_xor(rq[r], msk, 64);
      }
    }
    float mu[2], rstd[2];
    #pragma unroll
    for (int r = 0; r < 2; ++r) {
      mu[r] = rs[r] * (1.0f / H);
      float var = rq[r] * (1.0f / H) - mu[r] * mu[r];
      rstd[r] = rsqrtf(var + 1e-3f);
    }
    #pragma unroll
    for (int c = 0; c < 16; ++c) {
      int n = tidn * 4 + (c >> 2) * 128 + (c & 3);
      float gm = gmf[n], bt = btf[n];
      #pragma unroll
      for (int r = 0; r < 2; ++r) {
        float tv = gm * ((acc[r][c] - mu[r]) * rstd[r]) + bt;
        outacc[r][c] = fmaf(selw, tv, outacc[r][c]);
      }
    }
    __syncthreads();  // protect sV/sX2/sB before next f overwrites
  }

  // write selected [MTOT, H]
  #pragma unroll
  for (int r = 0; r < 2; ++r) {
    int row = row0 + m0 + r;
    #pragma unroll
    for (int cg = 0; cg < 4; ++cg) {
      int n = tidn * 4 + cg * 128;
      float4 o;
      o.x = outacc[r][cg * 4 + 0];
      o.y = outacc[r][cg * 4 + 1];
      o.z = outacc[r][cg * 4 + 2];
      o.w = outacc[r][cg * 4 + 3];
      *(float4*)&out[(size_t)row * H + n] = o;
    }
  }
}

extern "C" void kernel_launch(void* const* d_in, const int* in_sizes, int n_in,
                              void* d_out, int out_size, void* d_ws, size_t ws_size,
                              hipStream_t stream) {
  const float* in_     = (const float*)d_in[0];
  const float* W1c     = (const float*)d_in[1];
  const float* b1c     = (const float*)d_in[2];
  const float* W2c     = (const float*)d_in[3];
  const float* b2c     = (const float*)d_in[4];
  const float* Wgc     = (const float*)d_in[5];
  const float* bgc     = (const float*)d_in[6];
  const float* gamma_c = (const float*)d_in[7];
  const float* beta_c  = (const float*)d_in[8];
  const float* Wsel    = (const float*)d_in[9];
  const float* bsel    = (const float*)d_in[10];
  const float* w1      = (const float*)d_in[11];
  const float* b1v     = (const float*)d_in[12];
  const float* W2      = (const float*)d_in[13];
  const float* b2v     = (const float*)d_in[14];
  const float* Wg      = (const float*)d_in[15];
  const float* bgv     = (const float*)d_in[16];
  const float* gma     = (const float*)d_in[17];
  const float* bta     = (const float*)d_in[18];

  float* out_sel = (float*)d_out;                      // [MTOT, H]
  float* out_w   = (float*)d_out + (size_t)MTOT * H;   // [B, T, 1, F]
  float* sel_ws  = (float*)d_ws;                       // [B, F]

  hipLaunchKernelGGL(ctx_grn_kernel, dim3(NB), dim3(512), 0, stream,
                     in_, W1c, b1c, W2c, b2c, Wgc, bgc, gamma_c, beta_c,
                     Wsel, bsel, sel_ws, out_w);
  hipLaunchKernelGGL(var_grn_kernel, dim3(MTOT / TM), dim3(NTHR), 0, stream,
                     in_, w1, b1v, W2, b2v, Wg, bgv, gma, bta, sel_ws, out_sel);
}

// Round 2
// 669.887 us; speedup vs baseline: 4.6345x; 4.6345x over previous
//
#include <hip/hip_runtime.h>
#include <math.h>

// VariableSelectionNetwork — round 1: bf16 MFMA rewrite of the var-GRN kernel.
// Structure: pack_weights (fp32->bf16, B-fragment-major in d_ws) -> ctx_grn
// (unchanged fp32, ~4us) -> vsn_mfma (512thr/8-wave blocks, M=64, two chained
// MFMA GEMMs per f with register-prefetched B from L2, A via 64KB swizzled LDS).

#define H 512
#define NF 4
#define NT 128
#define NB 256
#define MTOT (NB * NT)   // 32768 rows (b,t)

typedef unsigned short u16;
typedef __attribute__((ext_vector_type(8))) short short8;   // 8 bf16 = 4 VGPRs
typedef __attribute__((ext_vector_type(4))) float f32x4;    // MFMA C/D

__device__ __forceinline__ u16 f2bf(float x) {
  union { float f; unsigned u; } v; v.f = x;
  return (u16)((v.u + 0x7fffu + ((v.u >> 16) & 1u)) >> 16);  // RNE
}
__device__ __forceinline__ float bf2f(u16 h) {
  union { unsigned u; float f; } v; v.u = ((unsigned)h) << 16;
  return v.f;
}
__device__ __forceinline__ float elu_f(float x) { return x > 0.0f ? x : expm1f(x); }
__device__ __forceinline__ float sigmoid_f(float x) { return 1.0f / (1.0f + expf(-x)); }

#define MFMA16(a, b, c) __builtin_amdgcn_mfma_f32_16x16x32_bf16((a), (b), (c), 0, 0, 0)

// ---------------- pack_weights: fp32 -> bf16 B-fragment-major ----------------
// Fragment layout for mfma_f32_16x16x32_bf16 B-operand: lane = n_local + 16*quad
// holds B[k = kk*32 + quad*8 + j][n = nt*16 + n_local], j = 0..7 contiguous.
// Packed index: ((((f*16 + kk)*32 + nt)*64 + lane)*8 + j)  per matrix.
__global__ __launch_bounds__(256)
void pack_weights(const float* __restrict__ W2, const float* __restrict__ Wg,
                  u16* __restrict__ W2p, u16* __restrict__ Wgp) {
  int t = blockIdx.x * 256 + threadIdx.x;   // 0 .. 262143
  int lane = t & 63;  int rest = t >> 6;
  int nt = rest & 31; rest >>= 5;
  int kk = rest & 15; rest >>= 4;
  int f  = rest & 3;  rest >>= 2;
  int mat = rest;                           // 0 = W2, 1 = Wg
  const float* W = (mat ? Wg : W2) + (size_t)f * H * H;
  u16* P = (mat ? Wgp : W2p) + ((((size_t)f * 16 + kk) * 32 + nt) * 64 + lane) * 8;
  int n  = nt * 16 + (lane & 15);
  int k0 = kk * 32 + (lane >> 4) * 8;
  short8 pk;
  #pragma unroll
  for (int j = 0; j < 8; ++j) pk[j] = (short)f2bf(W[(size_t)(k0 + j) * H + n]);
  *(short8*)P = pk;
}

// ---------------- Kernel A: context GRN + softmax selection ----------------
__global__ __launch_bounds__(512)
void ctx_grn_kernel(const float* __restrict__ in,
                    const float* __restrict__ W1c, const float* __restrict__ b1c,
                    const float* __restrict__ W2c, const float* __restrict__ b2c,
                    const float* __restrict__ Wgc, const float* __restrict__ bgc,
                    const float* __restrict__ gamma_c, const float* __restrict__ beta_c,
                    const float* __restrict__ Wsel, const float* __restrict__ bsel,
                    float* __restrict__ sel_ws,      // [B, F]
                    float* __restrict__ selw_out)    // [B, T, 1, F] flat
{
  __shared__ float sFlat[H];
  __shared__ float sX[H];
  __shared__ float sX2[H];
  __shared__ float sPartS[8], sPartQ[8];
  __shared__ float sLog[8][NF];
  __shared__ float sSel[NF];

  const int b = blockIdx.x;
  const int tid = threadIdx.x;

  sFlat[tid] = in[b * H + tid];
  __syncthreads();

  float acc = b1c[tid];
  #pragma unroll 8
  for (int d = 0; d < H; ++d) acc = fmaf(sFlat[d], W1c[d * H + tid], acc);
  sX[tid] = elu_f(acc);
  __syncthreads();

  acc = b2c[tid];
  #pragma unroll 8
  for (int d = 0; d < H; ++d) acc = fmaf(sX[d], W2c[d * H + tid], acc);
  sX2[tid] = acc;
  __syncthreads();

  acc = bgc[tid];
  #pragma unroll 8
  for (int d = 0; d < H; ++d) acc = fmaf(sX2[d], Wgc[d * H + tid], acc);
  const float g = sigmoid_f(acc);
  const float y = g * sX2[tid] + (1.0f - g) * sFlat[tid];

  float s = y, q = y * y;
  #pragma unroll
  for (int m = 32; m >= 1; m >>= 1) { s += __shfl_xor(s, m, 64); q += __shfl_xor(q, m, 64); }
  const int wid = tid >> 6;
  if ((tid & 63) == 0) { sPartS[wid] = s; sPartQ[wid] = q; }
  __syncthreads();
  s = 0.0f; q = 0.0f;
  #pragma unroll
  for (int w = 0; w < 8; ++w) { s += sPartS[w]; q += sPartQ[w]; }
  const float mean = s * (1.0f / H);
  const float var  = q * (1.0f / H) - mean * mean;
  const float rstd = rsqrtf(var + 1e-3f);
  const float ctx  = gamma_c[tid] * ((y - mean) * rstd) + beta_c[tid];

  float p0 = ctx * Wsel[tid * NF + 0];
  float p1 = ctx * Wsel[tid * NF + 1];
  float p2 = ctx * Wsel[tid * NF + 2];
  float p3 = ctx * Wsel[tid * NF + 3];
  #pragma unroll
  for (int m = 32; m >= 1; m >>= 1) {
    p0 += __shfl_xor(p0, m, 64); p1 += __shfl_xor(p1, m, 64);
    p2 += __shfl_xor(p2, m, 64); p3 += __shfl_xor(p3, m, 64);
  }
  if ((tid & 63) == 0) { sLog[wid][0] = p0; sLog[wid][1] = p1; sLog[wid][2] = p2; sLog[wid][3] = p3; }
  __syncthreads();
  if (tid == 0) {
    float z[NF];
    for (int f = 0; f < NF; ++f) {
      float t = bsel[f];
      for (int w = 0; w < 8; ++w) t += sLog[w][f];
      z[f] = t;
    }
    float mx = fmaxf(fmaxf(z[0], z[1]), fmaxf(z[2], z[3]));
    float e[NF]; float se = 0.0f;
    for (int f = 0; f < NF; ++f) { e[f] = expf(z[f] - mx); se += e[f]; }
    float inv = 1.0f / se;
    for (int f = 0; f < NF; ++f) sSel[f] = e[f] * inv;
  }
  __syncthreads();
  if (tid < NF) sel_ws[b * NF + tid] = sSel[tid];
  selw_out[b * H + tid] = sSel[tid & 3];
}

// ---------------- Kernel B: MFMA var-GRNs + weighted selection ----------------
// 512 threads = 8 waves. Block M-tile = 64 rows; wave owns 64 cols (4 n-tiles),
// 4 m-tiles -> 4x4 fragment grid. sA: 64KB LDS, XOR-swizzled [m][k] bf16,
// reused as A1 (GEMM1 A), then X2 (GEMM2 A + gate skip), then LN partials.
__global__ __launch_bounds__(512, 2)
void vsn_mfma(const float* __restrict__ in,     // [MTOT, F]
              const float* __restrict__ w1, const float* __restrict__ b1,
              const float* __restrict__ b2, const float* __restrict__ bg,
              const float* __restrict__ gamma, const float* __restrict__ beta,
              const u16* __restrict__ W2p, const u16* __restrict__ Wgp,
              const float* __restrict__ sel_ws,  // [B, F]
              float* __restrict__ out)           // [MTOT, H]
{
  __shared__ u16 sA[64 * H];            // 65536 B exactly
  float* sRed = (float*)sA;             // overlay: [row][wave] float2 = 4 KB

  const int tid  = threadIdx.x;
  const int wid  = tid >> 6;            // 0..7 : wave's n-slice
  const int lane = tid & 63;
  const int quad = lane >> 4;
  const int col  = lane & 15;
  const int row0 = blockIdx.x * 64;
  const int bidx = row0 >> 7;           // batch index (64 | 128)

  f32x4 outacc[4][4];
  #pragma unroll
  for (int mt = 0; mt < 4; ++mt)
    #pragma unroll
    for (int nt = 0; nt < 4; ++nt) outacc[mt][nt] = (f32x4){0.f, 0.f, 0.f, 0.f};

  for (int f = 0; f < NF; ++f) {
    // ---------- phase A1: sA[m][k] = bf16(elu(v[m]*w1[k] + b1[k])) ----------
    {
      const int m  = tid >> 3;             // 64 rows, 8 threads per row
      const int k0 = (tid & 7) * 64;       // 64 k per thread
      const float v = in[(row0 + m) * NF + f];
      const float* w1f = w1 + f * H;
      const float* b1f = b1 + f * H;
      #pragma unroll
      for (int gg = 0; gg < 8; ++gg) {
        const int k = k0 + gg * 8;
        short8 pk;
        #pragma unroll
        for (int j = 0; j < 8; ++j)
          pk[j] = (short)f2bf(elu_f(fmaf(v, w1f[k + j], b1f[k + j])));
        const int grp = (k >> 3) ^ (m & 7);               // XOR swizzle (16B units)
        *(short8*)&sA[m * H + (grp << 3)] = pk;
      }
    }
    __syncthreads();

    f32x4 acc[4][4];
    short8 Bb[3][4];

    // ================= GEMM1: X2 = A1 @ W2f =================
    {
      const u16* Bp = W2p + (size_t)f * (16 * 32 * 512);
      #pragma unroll
      for (int mt = 0; mt < 4; ++mt)
        #pragma unroll
        for (int nt = 0; nt < 4; ++nt) acc[mt][nt] = (f32x4){0.f, 0.f, 0.f, 0.f};
      // prefetch chunks 0,1
      #pragma unroll
      for (int s = 0; s < 2; ++s) {
        const u16* p = Bp + ((size_t)(s * 32 + wid * 4)) * 512 + lane * 8;
        #pragma unroll
        for (int nt = 0; nt < 4; ++nt) Bb[s][nt] = *(const short8*)(p + nt * 512);
      }
      #pragma unroll
      for (int kk = 0; kk < 16; ++kk) {
        if (kk < 14) {
          const int s = (kk + 2) % 3;
          const u16* p = Bp + ((size_t)((kk + 2) * 32 + wid * 4)) * 512 + lane * 8;
          #pragma unroll
          for (int nt = 0; nt < 4; ++nt) Bb[s][nt] = *(const short8*)(p + nt * 512);
        }
        short8 a[4];
        #pragma unroll
        for (int mt = 0; mt < 4; ++mt) {
          const int m = mt * 16 + col;
          const int grp = (kk * 4 + quad) ^ (m & 7);
          a[mt] = *(const short8*)&sA[m * H + (grp << 3)];
        }
        const int cs = kk % 3;
        #pragma unroll
        for (int mt = 0; mt < 4; ++mt)
          #pragma unroll
          for (int nt = 0; nt < 4; ++nt)
            acc[mt][nt] = MFMA16(a[mt], Bb[cs][nt], acc[mt][nt]);
      }
    }

    // ---------- epilogue1: X2 = acc + b2 -> sA (bf16, swizzled) ----------
    __syncthreads();   // everyone done reading A1
    {
      float b2v[4];
      #pragma unroll
      for (int nt = 0; nt < 4; ++nt) b2v[nt] = b2[f * H + wid * 64 + nt * 16 + col];
      #pragma unroll
      for (int mt = 0; mt < 4; ++mt)
        #pragma unroll
        for (int reg = 0; reg < 4; ++reg) {
          const int m = mt * 16 + quad * 4 + reg;
          #pragma unroll
          for (int nt = 0; nt < 4; ++nt) {
            const int n = wid * 64 + nt * 16 + col;
            const float x2 = acc[mt][nt][reg] + b2v[nt];
            sA[m * H + (((n >> 3) ^ (m & 7)) << 3) + (n & 7)] = f2bf(x2);
          }
        }
    }
    __syncthreads();

    // ================= GEMM2: Gpre = X2 @ Wgf =================
    {
      const u16* Bp = Wgp + (size_t)f * (16 * 32 * 512);
      #pragma unroll
      for (int mt = 0; mt < 4; ++mt)
        #pragma unroll
        for (int nt = 0; nt < 4; ++nt) acc[mt][nt] = (f32x4){0.f, 0.f, 0.f, 0.f};
      #pragma unroll
      for (int s = 0; s < 2; ++s) {
        const u16* p = Bp + ((size_t)(s * 32 + wid * 4)) * 512 + lane * 8;
        #pragma unroll
        for (int nt = 0; nt < 4; ++nt) Bb[s][nt] = *(const short8*)(p + nt * 512);
      }
      #pragma unroll
      for (int kk = 0; kk < 16; ++kk) {
        if (kk < 14) {
          const int s = (kk + 2) % 3;
          const u16* p = Bp + ((size_t)((kk + 2) * 32 + wid * 4)) * 512 + lane * 8;
          #pragma unroll
          for (int nt = 0; nt < 4; ++nt) Bb[s][nt] = *(const short8*)(p + nt * 512);
        }
        short8 a[4];
        #pragma unroll
        for (int mt = 0; mt < 4; ++mt) {
          const int m = mt * 16 + col;
          const int grp = (kk * 4 + quad) ^ (m & 7);
          a[mt] = *(const short8*)&sA[m * H + (grp << 3)];
        }
        const int cs = kk % 3;
        #pragma unroll
        for (int mt = 0; mt < 4; ++mt)
          #pragma unroll
          for (int nt = 0; nt < 4; ++nt)
            acc[mt][nt] = MFMA16(a[mt], Bb[cs][nt], acc[mt][nt]);
      }
    }

    // ---------- gate + LN + selection-weighted accumulate ----------
    {
      const float selw = sel_ws[bidx * NF + f];
      float bgv[4];
      #pragma unroll
      for (int nt = 0; nt < 4; ++nt) bgv[nt] = bg[f * H + wid * 64 + nt * 16 + col];
      float vr[4][4];
      #pragma unroll
      for (int mt = 0; mt < 4; ++mt)
        #pragma unroll
        for (int reg = 0; reg < 4; ++reg)
          vr[mt][reg] = in[(row0 + mt * 16 + quad * 4 + reg) * NF + f];

      float rs[4][4], rq[4][4];
      #pragma unroll
      for (int mt = 0; mt < 4; ++mt)
        #pragma unroll
        for (int reg = 0; reg < 4; ++reg) { rs[mt][reg] = 0.f; rq[mt][reg] = 0.f; }

      #pragma unroll
      for (int mt = 0; mt < 4; ++mt)
        #pragma unroll
        for (int reg = 0; reg < 4; ++reg) {
          const int m = mt * 16 + quad * 4 + reg;
          #pragma unroll
          for (int nt = 0; nt < 4; ++nt) {
            const int n = wid * 64 + nt * 16 + col;
            const float x2 = bf2f(sA[m * H + (((n >> 3) ^ (m & 7)) << 3) + (n & 7)]);
            const float gv = sigmoid_f(acc[mt][nt][reg] + bgv[nt]);
            const float gt = gv * x2 + (1.0f - gv) * vr[mt][reg];
            acc[mt][nt][reg] = gt;
            rs[mt][reg] += gt; rq[mt][reg] += gt * gt;
          }
        }
      // reduce across the 16 col-lanes (rows live on all lanes sharing quad)
      #pragma unroll
      for (int msk = 8; msk >= 1; msk >>= 1)
        #pragma unroll
        for (int mt = 0; mt < 4; ++mt)
          #pragma unroll
          for (int reg = 0; reg < 4; ++reg) {
            rs[mt][reg] += __shfl_xor(rs[mt][reg], msk, 64);
            rq[mt][reg] += __shfl_xor(rq[mt][reg], msk, 64);
          }
      __syncthreads();   // all x2 reads of sA done; safe to overlay sRed
      if (col == 0) {
        #pragma unroll
        for (int mt = 0; mt < 4; ++mt)
          #pragma unroll
          for (int reg = 0; reg < 4; ++reg) {
            const int m = mt * 16 + quad * 4 + reg;
            float2 sq; sq.x = rs[mt][reg]; sq.y = rq[mt][reg];
            *(float2*)&sRed[m * 16 + wid * 2] = sq;
          }
      }
      __syncthreads();

      float gmv[4], btv[4];
      #pragma unroll
      for (int nt = 0; nt < 4; ++nt) {
        const int n = wid * 64 + nt * 16 + col;
        gmv[nt] = gamma[f * H + n];
        btv[nt] = beta[f * H + n];
      }
      #pragma unroll
      for (int mt = 0; mt < 4; ++mt)
        #pragma unroll
        for (int reg = 0; reg < 4; ++reg) {
          const int m = mt * 16 + quad * 4 + reg;
          float s = 0.f, q = 0.f;
          #pragma unroll
          for (int w = 0; w < 8; ++w) {
            float2 sq = *(float2*)&sRed[m * 16 + w * 2];
            s += sq.x; q += sq.y;
          }
          const float mu   = s * (1.0f / H);
          const float rstd = rsqrtf(q * (1.0f / H) - mu * mu + 1e-3f);
          #pragma unroll
          for (int nt = 0; nt < 4; ++nt) {
            const float tv = gmv[nt] * ((acc[mt][nt][reg] - mu) * rstd) + btv[nt];
            outacc[mt][nt][reg] = fmaf(selw, tv, outacc[mt][nt][reg]);
          }
        }
      __syncthreads();   // sRed reads done before next f's A1 overwrites sA
    }
  }

  // ---------- store selected [MTOT, H] ----------
  #pragma unroll
  for (int mt = 0; mt < 4; ++mt)
    #pragma unroll
    for (int reg = 0; reg < 4; ++reg) {
      const int m = row0 + mt * 16 + quad * 4 + reg;
      #pragma unroll
      for (int nt = 0; nt < 4; ++nt) {
        const int n = wid * 64 + nt * 16 + col;
        out[(size_t)m * H + n] = outacc[mt][nt][reg];
      }
    }
}

extern "C" void kernel_launch(void* const* d_in, const int* in_sizes, int n_in,
                              void* d_out, int out_size, void* d_ws, size_t ws_size,
                              hipStream_t stream) {
  const float* in_     = (const float*)d_in[0];
  const float* W1c     = (const float*)d_in[1];
  const float* b1c     = (const float*)d_in[2];
  const float* W2c     = (const float*)d_in[3];
  const float* b2c     = (const float*)d_in[4];
  const float* Wgc     = (const float*)d_in[5];
  const float* bgc     = (const float*)d_in[6];
  const float* gamma_c = (const float*)d_in[7];
  const float* beta_c  = (const float*)d_in[8];
  const float* Wsel    = (const float*)d_in[9];
  const float* bsel    = (const float*)d_in[10];
  const float* w1      = (const float*)d_in[11];
  const float* b1v     = (const float*)d_in[12];
  const float* W2      = (const float*)d_in[13];
  const float* b2v     = (const float*)d_in[14];
  const float* Wg      = (const float*)d_in[15];
  const float* bgv     = (const float*)d_in[16];
  const float* gma     = (const float*)d_in[17];
  const float* bta     = (const float*)d_in[18];

  float* out_sel = (float*)d_out;                      // [MTOT, H]
  float* out_w   = (float*)d_out + (size_t)MTOT * H;   // [B, T, 1, F]

  float* sel_ws = (float*)d_ws;                                  // 4 KB
  u16*   W2p    = (u16*)((char*)d_ws + 4096);                    // 2 MB
  u16*   Wgp    = W2p + (size_t)NF * H * H;                      // 2 MB

  hipLaunchKernelGGL(pack_weights, dim3(1024), dim3(256), 0, stream, W2, Wg, W2p, Wgp);
  hipLaunchKernelGGL(ctx_grn_kernel, dim3(NB), dim3(512), 0, stream,
                     in_, W1c, b1c, W2c, b2c, Wgc, bgc, gamma_c, beta_c,
                     Wsel, bsel, sel_ws, out_w);
  hipLaunchKernelGGL(vsn_mfma, dim3(MTOT / 64), dim3(512), 0, stream,
                     in_, w1, b1v, b2v, bgv, gma, bta, W2p, Wgp, sel_ws, out_sel);
}